// Round 8
// baseline (209.686 us; speedup 1.0000x reference)
//
#include <hip/hip_runtime.h>
#include <hip/hip_bf16.h>

typedef short short8 __attribute__((ext_vector_type(8)));
typedef short short4v __attribute__((ext_vector_type(4)));
typedef float f32x4 __attribute__((ext_vector_type(4)));

#define S_LEN 2048
#define DIM   512
#define NBATCH 4

typedef unsigned short ushort_t;

__device__ __forceinline__ float b2f(unsigned short u) {
    union { unsigned u; float f; } x; x.u = ((unsigned)u) << 16; return x.f;
}
__device__ __forceinline__ unsigned short f2b(float f) {
    union { float f; unsigned u; } x; x.f = f;
    unsigned r = x.u + 0x7FFFu + ((x.u >> 16) & 1u);
    return (unsigned short)(r >> 16);
}
__device__ __forceinline__ float wave_sum(float v) {
    #pragma unroll
    for (int off = 32; off > 0; off >>= 1) v += __shfl_xor(v, off, 64);
    return v;
}
// Async global->LDS, 16B per lane; LDS dest = wave-uniform base + lane*16.
__device__ __forceinline__ void gld16(const void* g, void* l) {
    __builtin_amdgcn_global_load_lds(
        (const __attribute__((address_space(1))) unsigned int*)g,
        (__attribute__((address_space(3))) unsigned int*)l, 16, 0, 0);
}

// ---------------------------------------------------------------------------
// K0: one-shot fp32 -> bf16 conversion of x and the three weight matrices.
// ---------------------------------------------------------------------------
__global__ void convert_kernel(const float* __restrict__ x,
                               const float* __restrict__ Wq,
                               const float* __restrict__ Wk,
                               const float* __restrict__ Wv,
                               ushort_t* __restrict__ xb,
                               ushort_t* __restrict__ Wb)
{
    const int blk = blockIdx.x;
    const float* src;
    ushort_t* dst;
    size_t off;
    if (blk < 2048) {
        src = x; dst = xb; off = (size_t)blk * 2048;
    } else {
        int w = (blk - 2048) >> 7;          // 0:Wq 1:Wk 2:Wv
        int r = (blk - 2048) & 127;
        src = (w == 0) ? Wq : (w == 1) ? Wk : Wv;
        dst = Wb + (size_t)w * DIM * DIM;
        off = (size_t)r * 2048;
    }
    size_t i = off + (size_t)threadIdx.x * 8;
    f32x4 a = *(const f32x4*)&src[i];
    f32x4 c = *(const f32x4*)&src[i + 4];
    short8 o;
    #pragma unroll
    for (int e = 0; e < 4; e++) {
        o[e]     = (short)f2b(a[e]);
        o[4 + e] = (short)f2b(c[e]);
    }
    *(short8*)&dst[i] = o;
}

// ---------------------------------------------------------------------------
// K1: projections — bf16 GEMM, R7 structure (hoisted staging pointers).
// z=0: Q, z=1: K, z=2: V transposed Vt[b][d][s]. Row-norms fused (z<2).
// ---------------------------------------------------------------------------
__global__ void proj_kernel(
    const ushort_t* __restrict__ xb,
    const ushort_t* __restrict__ Wb,
    const float* __restrict__ bq, const float* __restrict__ bk,
    const float* __restrict__ bv,
    ushort_t* __restrict__ Q, ushort_t* __restrict__ Kp,
    ushort_t* __restrict__ Vt,
    float* __restrict__ nq, float* __restrict__ nk)
{
    __shared__ __align__(16) ushort_t As[128 * 32];
    __shared__ __align__(16) ushort_t Bs[128 * 32];
    const int z = blockIdx.z;
    const ushort_t* A  = xb;
    const ushort_t* Bt = Wb + (size_t)z * DIM * DIM;
    const float* bias = (z == 0) ? bq : (z == 1) ? bk : bv;

    const int bm0 = blockIdx.x * 128, bn0 = blockIdx.y * 128;
    const int tid = threadIdx.x;
    const int lane = tid & 63, wave = tid >> 6;
    const int wm = wave >> 1, wn = wave & 1;
    const int quad = lane >> 4;
    const int mrow = wm * 64 + (lane & 15);
    const int ncol = wn * 64 + (lane & 15);
    f32x4 acc[4][4] = {};

    const int f0 = tid, f1 = 256 + tid;
    const int rA0 = f0 >> 2, cA0 = (f0 & 3) ^ ((rA0 >> 1) & 3);
    const int rA1 = f1 >> 2, cA1 = (f1 & 3) ^ ((rA1 >> 1) & 3);
    const ushort_t* aP0 = A  + (size_t)(bm0 + rA0) * DIM + cA0 * 8;
    const ushort_t* aP1 = A  + (size_t)(bm0 + rA1) * DIM + cA1 * 8;
    const ushort_t* bP0 = Bt + (size_t)(bn0 + rA0) * DIM + cA0 * 8;
    const ushort_t* bP1 = Bt + (size_t)(bn0 + rA1) * DIM + cA1 * 8;
    ushort_t* dA0 = &As[(wave * 64) * 8];
    ushort_t* dA1 = &As[(256 + wave * 64) * 8];
    ushort_t* dB0 = &Bs[(wave * 64) * 8];
    ushort_t* dB1 = &Bs[(256 + wave * 64) * 8];

    for (int t = 0; t < 16; t++) {
        __syncthreads();
        gld16(aP0, dA0); gld16(aP1, dA1);
        gld16(bP0, dB0); gld16(bP1, dB1);
        aP0 += 32; aP1 += 32; bP0 += 32; bP1 += 32;
        __syncthreads();

        short8 af[4], bf[4];
        #pragma unroll
        for (int i = 0; i < 4; i++) {
            int row = mrow + 16 * i;
            af[i] = *(const short8*)&As[row * 32 + (quad ^ ((row >> 1) & 3)) * 8];
        }
        #pragma unroll
        for (int j = 0; j < 4; j++) {
            int row = ncol + 16 * j;
            bf[j] = *(const short8*)&Bs[row * 32 + (quad ^ ((row >> 1) & 3)) * 8];
        }
        #pragma unroll
        for (int i = 0; i < 4; i++)
            #pragma unroll
            for (int j = 0; j < 4; j++)
                acc[i][j] = __builtin_amdgcn_mfma_f32_16x16x32_bf16(
                    af[i], bf[j], acc[i][j], 0, 0, 0);
    }

    if (z < 2) {
        ushort_t* O = (z == 0) ? Q : Kp;
        float* nrm  = (z == 0) ? nq : nk;
        float ss[16] = {};
        #pragma unroll
        for (int j = 0; j < 4; j++) {
            int gcol = bn0 + wn * 64 + 16 * j + (lane & 15);
            float bb = bias[gcol];
            #pragma unroll
            for (int i = 0; i < 4; i++)
                #pragma unroll
                for (int r = 0; r < 4; r++) {
                    int grow = bm0 + wm * 64 + 16 * i + quad * 4 + r;
                    ushort_t ub = f2b(acc[i][j][r] + bb);
                    O[(size_t)grow * DIM + gcol] = ub;
                    float vr = b2f(ub);         // squared AFTER rounding
                    ss[i * 4 + r] += vr * vr;
                }
        }
        #pragma unroll
        for (int i = 0; i < 4; i++)
            #pragma unroll
            for (int r = 0; r < 4; r++) {
                float s = ss[i * 4 + r];
                s += __shfl_xor(s, 1, 64);
                s += __shfl_xor(s, 2, 64);
                s += __shfl_xor(s, 4, 64);
                s += __shfl_xor(s, 8, 64);
                if ((lane & 15) == 0) {
                    int grow = bm0 + wm * 64 + 16 * i + quad * 4 + r;
                    atomicAdd(&nrm[grow], s);
                }
            }
    } else {
        #pragma unroll
        for (int j = 0; j < 4; j++) {
            int gcol = bn0 + wn * 64 + 16 * j + (lane & 15);
            float bb = bias[gcol];
            #pragma unroll
            for (int i = 0; i < 4; i++) {
                int grow0 = bm0 + wm * 64 + 16 * i + quad * 4;
                int bb2 = grow0 >> 11, s = grow0 & 2047;
                short4v o4;
                #pragma unroll
                for (int r = 0; r < 4; r++) o4[r] = (short)f2b(acc[i][j][r] + bb);
                *(short4v*)&Vt[((size_t)bb2 * DIM + gcol) * S_LEN + s] = o4;
            }
        }
    }
}

// ---------------------------------------------------------------------------
// K3: score — REWRITTEN at 256x256 tile, BK=64, 512 threads / 8 waves
// (2M x 4N, per-wave 128x64 output, acc[8][4]). Single-buffer 2-barrier
// loop (proven-safe). Chunk swizzle: LDS chunk w of row r holds global
// k-chunk w^(r&7); read uses same involution -> ~2-way conflicts (free).
// K order unchanged (bitwise-identical qk vs the 128² version).
// Grid: (8, 8, NBATCH). LDS 64KB.
// ---------------------------------------------------------------------------
__global__ __launch_bounds__(512) void score_kernel(
                             const ushort_t* __restrict__ Q,
                             const ushort_t* __restrict__ Kp,
                             const float* __restrict__ nq,
                             const float* __restrict__ nk,
                             ushort_t* __restrict__ attnb,
                             float* __restrict__ NC)
{
    __shared__ __align__(16) ushort_t As[256 * 64];
    __shared__ __align__(16) ushort_t Bs[256 * 64];
    const int b = blockIdx.z;
    const ushort_t* A  = Q  + (size_t)b * S_LEN * DIM;
    const ushort_t* Bt = Kp + (size_t)b * S_LEN * DIM;
    const int bm0 = blockIdx.x * 256, bn0 = blockIdx.y * 256;
    const int tid = threadIdx.x;
    const int lane = tid & 63, wave = tid >> 6;   // 8 waves
    const int wm = wave >> 2, wn = wave & 3;      // 2M x 4N, wave tile 128x64
    const int quad = lane >> 4;
    f32x4 acc[8][4] = {};

    // staging: 4 chunks per matrix per thread (2048 chunks / 512 thr),
    // hoisted pointers; source pre-swizzled: chunk f -> row=f>>3,
    // c8=(f&7)^(row&7). LDS linear dest (wave-uniform base + lane*16).
    const ushort_t* aP[4];
    const ushort_t* bP[4];
    ushort_t* dA[4];
    ushort_t* dB[4];
    #pragma unroll
    for (int u = 0; u < 4; u++) {
        int f = u * 512 + tid;
        int row = f >> 3, c8 = (f & 7) ^ (row & 7);
        aP[u] = A  + (size_t)(bm0 + row) * DIM + c8 * 8;
        bP[u] = Bt + (size_t)(bn0 + row) * DIM + c8 * 8;
        dA[u] = &As[(u * 512 + wave * 64) * 8];
        dB[u] = &Bs[(u * 512 + wave * 64) * 8];
    }

    for (int t = 0; t < 8; t++) {           // K = 512 = 8 x BK64
        __syncthreads();
        #pragma unroll
        for (int u = 0; u < 4; u++) { gld16(aP[u], dA[u]); aP[u] += 64; }
        #pragma unroll
        for (int u = 0; u < 4; u++) { gld16(bP[u], dB[u]); bP[u] += 64; }
        __syncthreads();

        #pragma unroll
        for (int ks = 0; ks < 2; ks++) {    // two 32-deep MFMA sub-steps
            short8 af[8], bf[4];
            #pragma unroll
            for (int i = 0; i < 8; i++) {
                int r = wm * 128 + (lane & 15) + 16 * i;
                int cc = (ks * 4 + quad) ^ (r & 7);
                af[i] = *(const short8*)&As[r * 64 + cc * 8];
            }
            #pragma unroll
            for (int j = 0; j < 4; j++) {
                int r = wn * 64 + (lane & 15) + 16 * j;
                int cc = (ks * 4 + quad) ^ (r & 7);
                bf[j] = *(const short8*)&Bs[r * 64 + cc * 8];
            }
            #pragma unroll
            for (int i = 0; i < 8; i++)
                #pragma unroll
                for (int j = 0; j < 4; j++)
                    acc[i][j] = __builtin_amdgcn_mfma_f32_16x16x32_bf16(
                        af[i], bf[j], acc[i][j], 0, 0, 0);
        }
    }

    ushort_t* ob = attnb + (size_t)b * S_LEN * S_LEN;
    float nqv[32], nkv[4];
    #pragma unroll
    for (int i = 0; i < 8; i++)
        #pragma unroll
        for (int r = 0; r < 4; r++)
            nqv[i * 4 + r] =
                nq[b * S_LEN + bm0 + wm * 128 + 16 * i + quad * 4 + r];
    #pragma unroll
    for (int j = 0; j < 4; j++)
        nkv[j] = nk[b * S_LEN + bn0 + wn * 64 + 16 * j + (lane & 15)];

    float cp[4] = {0.f, 0.f, 0.f, 0.f};
    #pragma unroll
    for (int i = 0; i < 8; i++)
        #pragma unroll
        for (int j = 0; j < 4; j++)
            #pragma unroll
            for (int r = 0; r < 4; r++) {
                int grow = bm0 + wm * 128 + 16 * i + quad * 4 + r;
                int gcol = bn0 + wn * 64 + 16 * j + (lane & 15);
                float sq = nqv[i * 4 + r] + nkv[j] - 2.0f * acc[i][j][r];
                sq = fmaxf(sq, 1e-12f);
                ushort_t ub = f2b(__expf(sq * (-1.0f / 512.0f)));
                ob[(size_t)grow * S_LEN + gcol] = ub;
                cp[j] += b2f(ub);  // bf16-consistent column partial
            }
    // reduce over quads (rows) then one atomic per (wave, lane<16, j)
    #pragma unroll
    for (int j = 0; j < 4; j++) {
        float v = cp[j];
        v += __shfl_xor(v, 16, 64);
        v += __shfl_xor(v, 32, 64);
        if (quad == 0) {
            int gcol = bn0 + wn * 64 + 16 * j + (lane & 15);
            atomicAdd(&NC[b * S_LEN + gcol], v);
        }
    }
}

// ---------------------------------------------------------------------------
// K4+K5 merged: grid (512, NBATCH), 512 threads.
//  blockIdx.x >= 256: Vt[b][d][s] *= rsqrt(NC[b*S+s])   (scale part)
//  blockIdx.x <  256: wave-per-row rowsum + fp32 probs (NT) + rr
// ---------------------------------------------------------------------------
__global__ void scale_rowsum_kernel(ushort_t* __restrict__ Vt,
                                    const float* __restrict__ NC,
                                    const ushort_t* __restrict__ attnb,
                                    float* __restrict__ probs,
                                    float* __restrict__ rr)
{
    if (blockIdx.x >= 256) {
        int vb = (blockIdx.x - 256) * 4 + blockIdx.y;
        size_t idx = ((size_t)vb * 512 + threadIdx.x) * 8;
        int s0 = (int)(idx & 2047);
        int b  = (int)(idx >> 20);            // 512*2048 elems per batch
        const float* cb = NC + (b << 11);
        short8 v = *(short8*)&Vt[idx];
        #pragma unroll
        for (int e = 0; e < 8; e++)
            v[e] = (short)f2b(b2f((ushort_t)v[e]) * rsqrtf(cb[s0 + e]));
        *(short8*)&Vt[idx] = v;
        return;
    }
    const int wave = threadIdx.x >> 6, lane = threadIdx.x & 63;
    const int s = blockIdx.x * 8 + wave, b = blockIdx.y;
    const size_t R = (size_t)b * S_LEN + s;
    const ushort_t* row = attnb + R * S_LEN;
    const float* cb = NC + (b << 11);

    float pv[4][8], acc = 0.f;
    #pragma unroll
    for (int c = 0; c < 4; c++) {
        int t = c * 512 + lane * 8;
        short8 av = *(const short8*)&row[t];
        #pragma unroll
        for (int e = 0; e < 8; e++) {
            pv[c][e] = b2f((ushort_t)av[e]) * rsqrtf(cb[t + e]);
            acc += pv[c][e];
        }
    }
    float rs = 1.0f / wave_sum(acc);

    float* prow = probs + R * S_LEN;
    #pragma unroll
    for (int c = 0; c < 4; c++) {
        int t = c * 512 + lane * 8;
        f32x4 o0, o1;
        #pragma unroll
        for (int e = 0; e < 4; e++) { o0[e] = pv[c][e] * rs; o1[e] = pv[c][4 + e] * rs; }
        __builtin_nontemporal_store(o0, (f32x4*)&prow[t]);
        __builtin_nontemporal_store(o1, (f32x4*)&prow[t + 4]);
    }
    if (lane == 0) rr[R] = rs;
}

// ---------------------------------------------------------------------------
// K6: out = r ⊙ (attnb · Vtc). 512 threads / 8 waves, wave tile 64x32,
// BM=128 BN=128 BK=32, single-buffer 2-barrier loop, SWAPPED mfma operands
// (acc r-values column-consecutive -> f32x4 NT stores). Hoisted staging ptrs.
// ---------------------------------------------------------------------------
__global__ void out_gemm_kernel(const ushort_t* __restrict__ attnb,
                                const ushort_t* __restrict__ Vtc,
                                const float* __restrict__ rr,
                                float* __restrict__ outp)
{
    __shared__ __align__(16) ushort_t As[128 * 32];
    __shared__ __align__(16) ushort_t Bs[128 * 32];
    const int b = blockIdx.z;
    const ushort_t* A  = attnb + (size_t)b * S_LEN * S_LEN;
    const ushort_t* Bt = Vtc + (size_t)b * DIM * S_LEN;
    const int bm0 = blockIdx.x * 128, bn0 = blockIdx.y * 128;
    const int tid = threadIdx.x;
    const int lane = tid & 63, wave = tid >> 6;   // 8 waves
    const int wm = wave >> 2, wn = wave & 3;      // 2 x 4, wave tile 64x32
    const int quad = lane >> 4;
    const int mrow = wm * 64 + (lane & 15);
    const int ncol = wn * 32 + (lane & 15);
    f32x4 acc[4][2] = {};

    const int f = tid;
    const int row = f >> 2, c4 = (f & 3) ^ ((row >> 1) & 3);
    const ushort_t* aP = A  + (size_t)(bm0 + row) * S_LEN + c4 * 8;
    const ushort_t* bP = Bt + (size_t)(bn0 + row) * S_LEN + c4 * 8;
    ushort_t* dA = &As[(wave * 64) * 8];
    ushort_t* dB = &Bs[(wave * 64) * 8];

    for (int t = 0; t < 64; t++) {
        __syncthreads();
        gld16(aP, dA);
        gld16(bP, dB);
        aP += 32; bP += 32;
        __syncthreads();

        short8 af[4], bf[2];
        #pragma unroll
        for (int i = 0; i < 4; i++) {
            int r2 = mrow + 16 * i;
            af[i] = *(const short8*)&As[r2 * 32 + (quad ^ ((r2 >> 1) & 3)) * 8];
        }
        #pragma unroll
        for (int j = 0; j < 2; j++) {
            int r2 = ncol + 16 * j;
            bf[j] = *(const short8*)&Bs[r2 * 32 + (quad ^ ((r2 >> 1) & 3)) * 8];
        }
        #pragma unroll
        for (int i = 0; i < 4; i++)
            #pragma unroll
            for (int j = 0; j < 2; j++)
                acc[i][j] = __builtin_amdgcn_mfma_f32_16x16x32_bf16(
                    bf[j], af[i], acc[i][j], 0, 0, 0);
        __syncthreads();
    }

    float* C = outp + (size_t)b * S_LEN * DIM;
    float rv[4];
    #pragma unroll
    for (int i = 0; i < 4; i++)
        rv[i] = rr[b * S_LEN + bm0 + wm * 64 + 16 * i + (lane & 15)];
    #pragma unroll
    for (int i = 0; i < 4; i++) {
        int grow = bm0 + wm * 64 + 16 * i + (lane & 15);
        #pragma unroll
        for (int j = 0; j < 2; j++) {
            int gc = bn0 + wn * 32 + 16 * j + quad * 4;
            f32x4 o;
            #pragma unroll
            for (int r = 0; r < 4; r++) o[r] = acc[i][j][r] * rv[i];
            __builtin_nontemporal_store(o, (f32x4*)&C[(size_t)grow * DIM + gc]);
        }
    }
}

extern "C" void kernel_launch(void* const* d_in, const int* in_sizes, int n_in,
                              void* d_out, int out_size, void* d_ws, size_t ws_size,
                              hipStream_t stream)
{
    const float* x  = (const float*)d_in[0];
    const float* Wq = (const float*)d_in[1];
    const float* bq = (const float*)d_in[2];
    const float* Wk = (const float*)d_in[3];
    const float* bk = (const float*)d_in[4];
    const float* Wv = (const float*)d_in[5];
    const float* bv = (const float*)d_in[6];

    float* out   = (float*)d_out;                          // [4][2048][512] fp32
    float* probs = out + (size_t)NBATCH * S_LEN * DIM;     // [4][2048][2048] fp32

    // Q,K bf16 parked in the out region (dead before out_gemm writes it).
    ushort_t* Qb = (ushort_t*)d_out;                   // [8192][512] bf16
    ushort_t* Kb = Qb + (size_t)8192 * DIM;            // [8192][512] bf16
    // xb, Wb parked at the head of the probs region (dead until rowsum part).
    ushort_t* xb = (ushort_t*)probs;                   // [8192][512] bf16 (8.4MB)
    ushort_t* Wb = xb + (size_t)8192 * DIM;            // [3][512][512] bf16 (1.5MB)
    // ws: Vt 8.4MB | attnb 16.8MB | small floats  (total ~25.4 MB)
    ushort_t* Vt    = (ushort_t*)d_ws;                 // [4][512][2048] bf16
    ushort_t* attnb = Vt + (size_t)NBATCH * DIM * S_LEN;  // [4][2048][2048] bf16
    float* nq = (float*)(attnb + (size_t)NBATCH * S_LEN * S_LEN);
    float* nk = nq + 8192;
    float* NC = nk + 8192;
    float* cc = NC + 8192;   // slot kept (unused)
    float* rr = cc + 8192;

    // zero nq, nk, NC in one shot (contiguous)
    hipMemsetAsync(nq, 0, 3 * 8192 * sizeof(float), stream);

    convert_kernel<<<2432, 256, 0, stream>>>(x, Wq, Wk, Wv, xb, Wb);
    proj_kernel<<<dim3(64, 4, 3), 256, 0, stream>>>(xb, Wb, bq, bk, bv,
                                                    Qb, Kb, Vt, nq, nk);
    score_kernel<<<dim3(8, 8, NBATCH), 512, 0, stream>>>(Qb, Kb, nq, nk,
                                                         attnb, NC);
    scale_rowsum_kernel<<<dim3(512, NBATCH), 512, 0, stream>>>(Vt, NC, attnb,
                                                               probs, rr);
    out_gemm_kernel<<<dim3(16, 4, NBATCH), 512, 0, stream>>>(attnb, Vt, rr, out);
}

// Round 9
// 209.173 us; speedup vs baseline: 1.0025x; 1.0025x over previous
//
#include <hip/hip_runtime.h>
#include <hip/hip_bf16.h>

typedef short short8 __attribute__((ext_vector_type(8)));
typedef short short4v __attribute__((ext_vector_type(4)));
typedef float f32x4 __attribute__((ext_vector_type(4)));

#define S_LEN 2048
#define DIM   512
#define NBATCH 4

typedef unsigned short ushort_t;

__device__ __forceinline__ float b2f(unsigned short u) {
    union { unsigned u; float f; } x; x.u = ((unsigned)u) << 16; return x.f;
}
__device__ __forceinline__ unsigned short f2b(float f) {
    union { float f; unsigned u; } x; x.f = f;
    unsigned r = x.u + 0x7FFFu + ((x.u >> 16) & 1u);
    return (unsigned short)(r >> 16);
}
__device__ __forceinline__ float wave_sum(float v) {
    #pragma unroll
    for (int off = 32; off > 0; off >>= 1) v += __shfl_xor(v, off, 64);
    return v;
}
// Async global->LDS, 16B per lane; LDS dest = wave-uniform base + lane*16.
__device__ __forceinline__ void gld16(const void* g, void* l) {
    __builtin_amdgcn_global_load_lds(
        (const __attribute__((address_space(1))) unsigned int*)g,
        (__attribute__((address_space(3))) unsigned int*)l, 16, 0, 0);
}

// ---------------------------------------------------------------------------
// K0: one-shot fp32 -> bf16 conversion of x and the three weight matrices.
// ---------------------------------------------------------------------------
__global__ void convert_kernel(const float* __restrict__ x,
                               const float* __restrict__ Wq,
                               const float* __restrict__ Wk,
                               const float* __restrict__ Wv,
                               ushort_t* __restrict__ xb,
                               ushort_t* __restrict__ Wb)
{
    const int blk = blockIdx.x;
    const float* src;
    ushort_t* dst;
    size_t off;
    if (blk < 2048) {
        src = x; dst = xb; off = (size_t)blk * 2048;
    } else {
        int w = (blk - 2048) >> 7;          // 0:Wq 1:Wk 2:Wv
        int r = (blk - 2048) & 127;
        src = (w == 0) ? Wq : (w == 1) ? Wk : Wv;
        dst = Wb + (size_t)w * DIM * DIM;
        off = (size_t)r * 2048;
    }
    size_t i = off + (size_t)threadIdx.x * 8;
    f32x4 a = *(const f32x4*)&src[i];
    f32x4 c = *(const f32x4*)&src[i + 4];
    short8 o;
    #pragma unroll
    for (int e = 0; e < 4; e++) {
        o[e]     = (short)f2b(a[e]);
        o[4 + e] = (short)f2b(c[e]);
    }
    *(short8*)&dst[i] = o;
}

// ---------------------------------------------------------------------------
// K1: projections — bf16 GEMM, R7 structure (hoisted staging pointers).
// z=0: Q, z=1: K, z=2: V transposed Vt[b][d][s]. Row-norms fused (z<2).
// ---------------------------------------------------------------------------
__global__ void proj_kernel(
    const ushort_t* __restrict__ xb,
    const ushort_t* __restrict__ Wb,
    const float* __restrict__ bq, const float* __restrict__ bk,
    const float* __restrict__ bv,
    ushort_t* __restrict__ Q, ushort_t* __restrict__ Kp,
    ushort_t* __restrict__ Vt,
    float* __restrict__ nq, float* __restrict__ nk)
{
    __shared__ __align__(16) ushort_t As[128 * 32];
    __shared__ __align__(16) ushort_t Bs[128 * 32];
    const int z = blockIdx.z;
    const ushort_t* A  = xb;
    const ushort_t* Bt = Wb + (size_t)z * DIM * DIM;
    const float* bias = (z == 0) ? bq : (z == 1) ? bk : bv;

    const int bm0 = blockIdx.x * 128, bn0 = blockIdx.y * 128;
    const int tid = threadIdx.x;
    const int lane = tid & 63, wave = tid >> 6;
    const int wm = wave >> 1, wn = wave & 1;
    const int quad = lane >> 4;
    const int mrow = wm * 64 + (lane & 15);
    const int ncol = wn * 64 + (lane & 15);
    f32x4 acc[4][4] = {};

    const int f0 = tid, f1 = 256 + tid;
    const int rA0 = f0 >> 2, cA0 = (f0 & 3) ^ ((rA0 >> 1) & 3);
    const int rA1 = f1 >> 2, cA1 = (f1 & 3) ^ ((rA1 >> 1) & 3);
    const ushort_t* aP0 = A  + (size_t)(bm0 + rA0) * DIM + cA0 * 8;
    const ushort_t* aP1 = A  + (size_t)(bm0 + rA1) * DIM + cA1 * 8;
    const ushort_t* bP0 = Bt + (size_t)(bn0 + rA0) * DIM + cA0 * 8;
    const ushort_t* bP1 = Bt + (size_t)(bn0 + rA1) * DIM + cA1 * 8;
    ushort_t* dA0 = &As[(wave * 64) * 8];
    ushort_t* dA1 = &As[(256 + wave * 64) * 8];
    ushort_t* dB0 = &Bs[(wave * 64) * 8];
    ushort_t* dB1 = &Bs[(256 + wave * 64) * 8];

    for (int t = 0; t < 16; t++) {
        __syncthreads();
        gld16(aP0, dA0); gld16(aP1, dA1);
        gld16(bP0, dB0); gld16(bP1, dB1);
        aP0 += 32; aP1 += 32; bP0 += 32; bP1 += 32;
        __syncthreads();

        short8 af[4], bf[4];
        #pragma unroll
        for (int i = 0; i < 4; i++) {
            int row = mrow + 16 * i;
            af[i] = *(const short8*)&As[row * 32 + (quad ^ ((row >> 1) & 3)) * 8];
        }
        #pragma unroll
        for (int j = 0; j < 4; j++) {
            int row = ncol + 16 * j;
            bf[j] = *(const short8*)&Bs[row * 32 + (quad ^ ((row >> 1) & 3)) * 8];
        }
        #pragma unroll
        for (int i = 0; i < 4; i++)
            #pragma unroll
            for (int j = 0; j < 4; j++)
                acc[i][j] = __builtin_amdgcn_mfma_f32_16x16x32_bf16(
                    af[i], bf[j], acc[i][j], 0, 0, 0);
    }

    if (z < 2) {
        ushort_t* O = (z == 0) ? Q : Kp;
        float* nrm  = (z == 0) ? nq : nk;
        float ss[16] = {};
        #pragma unroll
        for (int j = 0; j < 4; j++) {
            int gcol = bn0 + wn * 64 + 16 * j + (lane & 15);
            float bb = bias[gcol];
            #pragma unroll
            for (int i = 0; i < 4; i++)
                #pragma unroll
                for (int r = 0; r < 4; r++) {
                    int grow = bm0 + wm * 64 + 16 * i + quad * 4 + r;
                    ushort_t ub = f2b(acc[i][j][r] + bb);
                    O[(size_t)grow * DIM + gcol] = ub;
                    float vr = b2f(ub);         // squared AFTER rounding
                    ss[i * 4 + r] += vr * vr;
                }
        }
        #pragma unroll
        for (int i = 0; i < 4; i++)
            #pragma unroll
            for (int r = 0; r < 4; r++) {
                float s = ss[i * 4 + r];
                s += __shfl_xor(s, 1, 64);
                s += __shfl_xor(s, 2, 64);
                s += __shfl_xor(s, 4, 64);
                s += __shfl_xor(s, 8, 64);
                if ((lane & 15) == 0) {
                    int grow = bm0 + wm * 64 + 16 * i + quad * 4 + r;
                    atomicAdd(&nrm[grow], s);
                }
            }
    } else {
        #pragma unroll
        for (int j = 0; j < 4; j++) {
            int gcol = bn0 + wn * 64 + 16 * j + (lane & 15);
            float bb = bias[gcol];
            #pragma unroll
            for (int i = 0; i < 4; i++) {
                int grow0 = bm0 + wm * 64 + 16 * i + quad * 4;
                int bb2 = grow0 >> 11, s = grow0 & 2047;
                short4v o4;
                #pragma unroll
                for (int r = 0; r < 4; r++) o4[r] = (short)f2b(acc[i][j][r] + bb);
                *(short4v*)&Vt[((size_t)bb2 * DIM + gcol) * S_LEN + s] = o4;
            }
        }
    }
}

// ---------------------------------------------------------------------------
// K3: score — R7 128² version (1024 blocks = 4/CU co-residency; measured
// best). attnb[s,t] = bf16(exp(-max(|q|^2+|k|^2-2qk, eps)/512)), fused
// column-sum atomics into NC. Hoisted staging pointers.
// ---------------------------------------------------------------------------
__global__ void score_kernel(const ushort_t* __restrict__ Q,
                             const ushort_t* __restrict__ Kp,
                             const float* __restrict__ nq,
                             const float* __restrict__ nk,
                             ushort_t* __restrict__ attnb,
                             float* __restrict__ NC)
{
    __shared__ __align__(16) ushort_t As[128 * 32];
    __shared__ __align__(16) ushort_t Bs[128 * 32];
    const int b = blockIdx.z;
    const ushort_t* A  = Q  + (size_t)b * S_LEN * DIM;
    const ushort_t* Bt = Kp + (size_t)b * S_LEN * DIM;
    const int bm0 = blockIdx.x * 128, bn0 = blockIdx.y * 128;
    const int tid = threadIdx.x;
    const int lane = tid & 63, wave = tid >> 6;
    const int wm = wave >> 1, wn = wave & 1;
    const int quad = lane >> 4;
    const int mrow = wm * 64 + (lane & 15);
    const int ncol = wn * 64 + (lane & 15);
    f32x4 acc[4][4] = {};

    const int f0 = tid, f1 = 256 + tid;
    const int rA0 = f0 >> 2, cA0 = (f0 & 3) ^ ((rA0 >> 1) & 3);
    const int rA1 = f1 >> 2, cA1 = (f1 & 3) ^ ((rA1 >> 1) & 3);
    const ushort_t* aP0 = A  + (size_t)(bm0 + rA0) * DIM + cA0 * 8;
    const ushort_t* aP1 = A  + (size_t)(bm0 + rA1) * DIM + cA1 * 8;
    const ushort_t* bP0 = Bt + (size_t)(bn0 + rA0) * DIM + cA0 * 8;
    const ushort_t* bP1 = Bt + (size_t)(bn0 + rA1) * DIM + cA1 * 8;
    ushort_t* dA0 = &As[(wave * 64) * 8];
    ushort_t* dA1 = &As[(256 + wave * 64) * 8];
    ushort_t* dB0 = &Bs[(wave * 64) * 8];
    ushort_t* dB1 = &Bs[(256 + wave * 64) * 8];

    for (int t = 0; t < 16; t++) {
        __syncthreads();
        gld16(aP0, dA0); gld16(aP1, dA1);
        gld16(bP0, dB0); gld16(bP1, dB1);
        aP0 += 32; aP1 += 32; bP0 += 32; bP1 += 32;
        __syncthreads();

        short8 af[4], bf[4];
        #pragma unroll
        for (int i = 0; i < 4; i++) {
            int row = mrow + 16 * i;
            af[i] = *(const short8*)&As[row * 32 + (quad ^ ((row >> 1) & 3)) * 8];
        }
        #pragma unroll
        for (int j = 0; j < 4; j++) {
            int row = ncol + 16 * j;
            bf[j] = *(const short8*)&Bs[row * 32 + (quad ^ ((row >> 1) & 3)) * 8];
        }
        #pragma unroll
        for (int i = 0; i < 4; i++)
            #pragma unroll
            for (int j = 0; j < 4; j++)
                acc[i][j] = __builtin_amdgcn_mfma_f32_16x16x32_bf16(
                    af[i], bf[j], acc[i][j], 0, 0, 0);
    }

    ushort_t* ob = attnb + (size_t)b * S_LEN * S_LEN;
    float nqv[16], nkv[4];
    #pragma unroll
    for (int i = 0; i < 4; i++)
        #pragma unroll
        for (int r = 0; r < 4; r++)
            nqv[i * 4 + r] = nq[b * S_LEN + bm0 + wm * 64 + 16 * i + quad * 4 + r];
    #pragma unroll
    for (int j = 0; j < 4; j++)
        nkv[j] = nk[b * S_LEN + bn0 + wn * 64 + 16 * j + (lane & 15)];

    float cp[4] = {0.f, 0.f, 0.f, 0.f};
    #pragma unroll
    for (int i = 0; i < 4; i++)
        #pragma unroll
        for (int j = 0; j < 4; j++)
            #pragma unroll
            for (int r = 0; r < 4; r++) {
                int grow = bm0 + wm * 64 + 16 * i + quad * 4 + r;
                int gcol = bn0 + wn * 64 + 16 * j + (lane & 15);
                float sq = nqv[i * 4 + r] + nkv[j] - 2.0f * acc[i][j][r];
                sq = fmaxf(sq, 1e-12f);
                ushort_t ub = f2b(__expf(sq * (-1.0f / 512.0f)));
                ob[(size_t)grow * S_LEN + gcol] = ub;
                cp[j] += b2f(ub);  // bf16-consistent column partial
            }
    #pragma unroll
    for (int j = 0; j < 4; j++) {
        float v = cp[j];
        v += __shfl_xor(v, 16, 64);
        v += __shfl_xor(v, 32, 64);
        if (quad == 0) {
            int gcol = bn0 + wn * 64 + 16 * j + (lane & 15);
            atomicAdd(&NC[b * S_LEN + gcol], v);
        }
    }
}

// ---------------------------------------------------------------------------
// K4+K5 merged: grid (512, NBATCH), 512 threads.
//  blockIdx.x >= 256: Vt[b][d][s] *= rsqrt(NC[b*S+s])   (scale part)
//  blockIdx.x <  256: wave-per-row rowsum + fp32 probs (NT) + rr
// ---------------------------------------------------------------------------
__global__ void scale_rowsum_kernel(ushort_t* __restrict__ Vt,
                                    const float* __restrict__ NC,
                                    const ushort_t* __restrict__ attnb,
                                    float* __restrict__ probs,
                                    float* __restrict__ rr)
{
    if (blockIdx.x >= 256) {
        int vb = (blockIdx.x - 256) * 4 + blockIdx.y;
        size_t idx = ((size_t)vb * 512 + threadIdx.x) * 8;
        int s0 = (int)(idx & 2047);
        int b  = (int)(idx >> 20);            // 512*2048 elems per batch
        const float* cb = NC + (b << 11);
        short8 v = *(short8*)&Vt[idx];
        #pragma unroll
        for (int e = 0; e < 8; e++)
            v[e] = (short)f2b(b2f((ushort_t)v[e]) * rsqrtf(cb[s0 + e]));
        *(short8*)&Vt[idx] = v;
        return;
    }
    const int wave = threadIdx.x >> 6, lane = threadIdx.x & 63;
    const int s = blockIdx.x * 8 + wave, b = blockIdx.y;
    const size_t R = (size_t)b * S_LEN + s;
    const ushort_t* row = attnb + R * S_LEN;
    const float* cb = NC + (b << 11);

    float pv[4][8], acc = 0.f;
    #pragma unroll
    for (int c = 0; c < 4; c++) {
        int t = c * 512 + lane * 8;
        short8 av = *(const short8*)&row[t];
        #pragma unroll
        for (int e = 0; e < 8; e++) {
            pv[c][e] = b2f((ushort_t)av[e]) * rsqrtf(cb[t + e]);
            acc += pv[c][e];
        }
    }
    float rs = 1.0f / wave_sum(acc);

    float* prow = probs + R * S_LEN;
    #pragma unroll
    for (int c = 0; c < 4; c++) {
        int t = c * 512 + lane * 8;
        f32x4 o0, o1;
        #pragma unroll
        for (int e = 0; e < 4; e++) { o0[e] = pv[c][e] * rs; o1[e] = pv[c][4 + e] * rs; }
        __builtin_nontemporal_store(o0, (f32x4*)&prow[t]);
        __builtin_nontemporal_store(o1, (f32x4*)&prow[t + 4]);
    }
    if (lane == 0) rr[R] = rs;
}

// ---------------------------------------------------------------------------
// K6: out = r ⊙ (attnb · Vtc). RESTRUCTURED for co-residency: BM=128 BN=64,
// 256 threads / 4 waves (wave tile 64x32), grid (16,8,4)=512 blocks = 2/CU
// (was 256 = 1/CU — the only GEMM with zero block overlap; m102 mechanism).
// Single-buffer 2-barrier loop, SWAPPED mfma operands -> f32x4 NT stores.
// LDS 12KB. Hoisted staging pointers.
// ---------------------------------------------------------------------------
__global__ void out_gemm_kernel(const ushort_t* __restrict__ attnb,
                                const ushort_t* __restrict__ Vtc,
                                const float* __restrict__ rr,
                                float* __restrict__ outp)
{
    __shared__ __align__(16) ushort_t As[128 * 32];
    __shared__ __align__(16) ushort_t Bs[64 * 32];
    const int b = blockIdx.z;
    const ushort_t* A  = attnb + (size_t)b * S_LEN * S_LEN;
    const ushort_t* Bt = Vtc + (size_t)b * DIM * S_LEN;
    const int bm0 = blockIdx.x * 128, bn0 = blockIdx.y * 64;
    const int tid = threadIdx.x;
    const int lane = tid & 63, wave = tid >> 6;   // 4 waves
    const int wm = wave >> 1, wn = wave & 1;      // 2 x 2, wave tile 64x32
    const int quad = lane >> 4;
    const int mrow = wm * 64 + (lane & 15);
    const int ncol = wn * 32 + (lane & 15);
    f32x4 acc[4][2] = {};

    // A: 512 chunks / 256 thr = 2 per thread; B: 256 chunks = 1 per thread.
    const int f0 = tid, f1 = 256 + tid;
    const int rA0 = f0 >> 2, cA0 = (f0 & 3) ^ ((rA0 >> 1) & 3);
    const int rA1 = f1 >> 2, cA1 = (f1 & 3) ^ ((rA1 >> 1) & 3);
    const ushort_t* aP0 = A  + (size_t)(bm0 + rA0) * S_LEN + cA0 * 8;
    const ushort_t* aP1 = A  + (size_t)(bm0 + rA1) * S_LEN + cA1 * 8;
    const ushort_t* bP  = Bt + (size_t)(bn0 + rA0) * S_LEN + cA0 * 8;
    ushort_t* dA0 = &As[(wave * 64) * 8];
    ushort_t* dA1 = &As[(256 + wave * 64) * 8];
    ushort_t* dB  = &Bs[(wave * 64) * 8];

    for (int t = 0; t < 64; t++) {
        __syncthreads();
        gld16(aP0, dA0); gld16(aP1, dA1);
        gld16(bP, dB);
        aP0 += 32; aP1 += 32; bP += 32;
        __syncthreads();

        short8 af[4], bf[2];
        #pragma unroll
        for (int i = 0; i < 4; i++) {
            int r2 = mrow + 16 * i;
            af[i] = *(const short8*)&As[r2 * 32 + (quad ^ ((r2 >> 1) & 3)) * 8];
        }
        #pragma unroll
        for (int j = 0; j < 2; j++) {
            int r2 = ncol + 16 * j;
            bf[j] = *(const short8*)&Bs[r2 * 32 + (quad ^ ((r2 >> 1) & 3)) * 8];
        }
        // swapped operands: D-row <-> bf row (gcol), D-col <-> af row (grow)
        #pragma unroll
        for (int i = 0; i < 4; i++)
            #pragma unroll
            for (int j = 0; j < 2; j++)
                acc[i][j] = __builtin_amdgcn_mfma_f32_16x16x32_bf16(
                    bf[j], af[i], acc[i][j], 0, 0, 0);
        __syncthreads();
    }

    float* C = outp + (size_t)b * S_LEN * DIM;
    float rv[4];
    #pragma unroll
    for (int i = 0; i < 4; i++)
        rv[i] = rr[b * S_LEN + bm0 + wm * 64 + 16 * i + (lane & 15)];
    #pragma unroll
    for (int i = 0; i < 4; i++) {
        int grow = bm0 + wm * 64 + 16 * i + (lane & 15);
        #pragma unroll
        for (int j = 0; j < 2; j++) {
            int gc = bn0 + wn * 32 + 16 * j + quad * 4;
            f32x4 o;
            #pragma unroll
            for (int r = 0; r < 4; r++) o[r] = acc[i][j][r] * rv[i];
            __builtin_nontemporal_store(o, (f32x4*)&C[(size_t)grow * DIM + gc]);
        }
    }
}

extern "C" void kernel_launch(void* const* d_in, const int* in_sizes, int n_in,
                              void* d_out, int out_size, void* d_ws, size_t ws_size,
                              hipStream_t stream)
{
    const float* x  = (const float*)d_in[0];
    const float* Wq = (const float*)d_in[1];
    const float* bq = (const float*)d_in[2];
    const float* Wk = (const float*)d_in[3];
    const float* bk = (const float*)d_in[4];
    const float* Wv = (const float*)d_in[5];
    const float* bv = (const float*)d_in[6];

    float* out   = (float*)d_out;                          // [4][2048][512] fp32
    float* probs = out + (size_t)NBATCH * S_LEN * DIM;     // [4][2048][2048] fp32

    // Q,K bf16 parked in the out region (dead before out_gemm writes it).
    ushort_t* Qb = (ushort_t*)d_out;                   // [8192][512] bf16
    ushort_t* Kb = Qb + (size_t)8192 * DIM;            // [8192][512] bf16
    // xb, Wb parked at the head of the probs region (dead until rowsum part).
    ushort_t* xb = (ushort_t*)probs;                   // [8192][512] bf16 (8.4MB)
    ushort_t* Wb = xb + (size_t)8192 * DIM;            // [3][512][512] bf16 (1.5MB)
    // ws: Vt 8.4MB | attnb 16.8MB | small floats  (total ~25.4 MB)
    ushort_t* Vt    = (ushort_t*)d_ws;                 // [4][512][2048] bf16
    ushort_t* attnb = Vt + (size_t)NBATCH * DIM * S_LEN;  // [4][2048][2048] bf16
    float* nq = (float*)(attnb + (size_t)NBATCH * S_LEN * S_LEN);
    float* nk = nq + 8192;
    float* NC = nk + 8192;
    float* cc = NC + 8192;   // slot kept (unused)
    float* rr = cc + 8192;

    // zero nq, nk, NC in one shot (contiguous)
    hipMemsetAsync(nq, 0, 3 * 8192 * sizeof(float), stream);

    convert_kernel<<<2432, 256, 0, stream>>>(x, Wq, Wk, Wv, xb, Wb);
    proj_kernel<<<dim3(64, 4, 3), 256, 0, stream>>>(xb, Wb, bq, bk, bv,
                                                    Qb, Kb, Vt, nq, nk);
    score_kernel<<<dim3(16, 16, NBATCH), 256, 0, stream>>>(Qb, Kb, nq, nk,
                                                           attnb, NC);
    scale_rowsum_kernel<<<dim3(512, NBATCH), 512, 0, stream>>>(Vt, NC, attnb,
                                                               probs, rr);
    out_gemm_kernel<<<dim3(16, 8, NBATCH), 256, 0, stream>>>(attnb, Vt, rr, out);
}